// Round 14
// baseline (294.872 us; speedup 1.0000x reference)
//
#include <hip/hip_runtime.h>
#include <hip/hip_bf16.h>
#include <math.h>

#define BB    1024
#define FIN   128
#define NOUT  10000
#define NBLK  79          // 128-col strips (fallback path)
#define NCB   158         // 64-col regions (Wbf layout)
#define NK    16
#define NP_FX (NCB * 4)   // fast-path partial stride: per (cb, wn4) = 632
#define NP_FB 316         // fallback partial stride
#define LDX   136         // LDS stride (shorts) for the X tile

typedef __attribute__((ext_vector_type(8))) short short8;
typedef __attribute__((ext_vector_type(4))) float floatx4;

__device__ __forceinline__ unsigned packbf(float a, float b) {
    __hip_bfloat162 h = __float22bfloat162_rn(make_float2(a, b));
    union { __hip_bfloat162 h2; unsigned u; } v;
    v.h2 = h;
    return v.u;
}

// unpack bf16 pair, scale, repack
__device__ __forceinline__ unsigned scale2(unsigned p, float wi) {
    float lo = __uint_as_float(p << 16) * wi;
    float hi = __uint_as_float(p & 0xffff0000u) * wi;
    return packbf(lo, hi);
}

// async global->LDS, 16B per lane; LDS dest = wave-uniform base + lane*16.
__device__ __forceinline__ void async16(const void* g, void* l) {
    __builtin_amdgcn_global_load_lds(
        (const __attribute__((address_space(1))) unsigned int*)g,
        (__attribute__((address_space(3))) unsigned int*)l, 16, 0, 0);
}

// ---------------------------------------------------------------------------
// Kernel A (fallback path only)
__global__ void rowprep(const float* __restrict__ X, const float* __restrict__ factor,
                        float* __restrict__ xinv, float* __restrict__ fa_out,
                        float* __restrict__ thr_out) {
    int b = blockIdx.x;
    int lane = threadIdx.x;
    float v0 = X[b * FIN + lane];
    float v1 = X[b * FIN + 64 + lane];
    float s = v0 * v0 + v1 * v1;
    #pragma unroll
    for (int off = 32; off > 0; off >>= 1) s += __shfl_down(s, off);
    if (lane == 0) {
        xinv[b] = 1.0f / fmaxf(sqrtf(s), 1e-12f);
        float fa = powf(1.5f, factor[b] * (1.0f / 12.0f)) * 0.5f;
        fa_out[b] = fa;
        thr_out[b] = (float)M_PI - fa;
    }
}

// ---------------------------------------------------------------------------
// Kernel W v3 (proven r13): f-half staging + deferred winv scale at copy-out.
// Wbf layout: per (k, cb64) 16 KB region [wn(2)][n2(2)][kk(4)][lane][16B]
// == linear in 16-col slot wn4 = wn*2+n2 at wn4*2048 bytes.
__global__ __launch_bounds__(256) void wconv(
    const float* __restrict__ W, unsigned char* __restrict__ Wbf,
    const float* __restrict__ X, const float* __restrict__ factor,
    float* __restrict__ xinv, float* __restrict__ fa_out, float* __restrict__ thr_out) {

    __shared__ float s[64 * 64];    // 16 KB: one f-half, [f][c] fp32
    __shared__ uint4 wout[1024];    // 16 KB packed (unscaled bf16)
    __shared__ float sq2[256];
    __shared__ float wis[64];

    const int tid = threadIdx.x;

    // rowprep tail blocks
    if (blockIdx.x >= NK * NCB) {
        int rb = blockIdx.x - NK * NCB;   // 0..15
        int w4 = tid >> 6, lane = tid & 63;
        for (int i = w4; i < 64; i += 4) {
            int row = rb * 64 + i;
            float v0 = X[row * FIN + lane];
            float v1 = X[row * FIN + 64 + lane];
            float ss = v0 * v0 + v1 * v1;
            #pragma unroll
            for (int off = 32; off > 0; off >>= 1) ss += __shfl_down(ss, off);
            if (lane == 0) {
                xinv[row] = 1.0f / fmaxf(sqrtf(ss), 1e-12f);
                float fa = powf(1.5f, factor[row] * (1.0f / 12.0f)) * 0.5f;
                fa_out[row] = fa;
                thr_out[row] = (float)M_PI - fa;
            }
        }
        return;
    }

    const int k  = blockIdx.x / NCB;
    const int cb = blockIdx.x - k * NCB;
    const int o0 = cb * 64;
    const int col = tid & 63, seg = tid >> 6;
    const int c   = tid >> 2, sub = tid & 3;
    const int wn_ = c >> 5, n2_ = (c >> 4) & 1, l15_ = c & 15;

    float sqacc = 0.0f;
    #pragma unroll
    for (int h = 0; h < 2; h++) {
        #pragma unroll
        for (int it = 0; it < 4; it++) {
            int idx = it * 256 + tid;      // float4 idx 0..1023
            int f = idx >> 4, c4 = idx & 15;
            int o = o0 + c4 * 4;
            float4 v = make_float4(0.f, 0.f, 0.f, 0.f);
            if (o < NOUT)
                v = *(const float4*)(W + (size_t)(k * FIN + h * 64 + f) * NOUT + o);
            *(float4*)(s + f * 64 + c4 * 4) = v;
        }
        __syncthreads();
        float ss = 0.0f;
        #pragma unroll
        for (int f2 = 0; f2 < 16; f2++) {
            float x = s[(seg * 16 + f2) * 64 + col];
            ss = fmaf(x, x, ss);
        }
        sqacc += ss;
        #pragma unroll
        for (int i = 0; i < 2; i++) {
            int tcl = sub * 2 + i;          // 0..7
            int tcg = h * 8 + tcl;          // 0..15
            int kk = tcg >> 2, qq = tcg & 3;
            int fb = tcl * 8;
            uint4 u;
            u.x = packbf(s[(fb + 0) * 64 + c], s[(fb + 1) * 64 + c]);
            u.y = packbf(s[(fb + 2) * 64 + c], s[(fb + 3) * 64 + c]);
            u.z = packbf(s[(fb + 4) * 64 + c], s[(fb + 5) * 64 + c]);
            u.w = packbf(s[(fb + 6) * 64 + c], s[(fb + 7) * 64 + c]);
            wout[wn_ * 512 + n2_ * 256 + kk * 64 + qq * 16 + l15_] = u;
        }
        __syncthreads();
    }
    sq2[tid] = sqacc;
    __syncthreads();
    if (tid < 64)
        wis[tid] = 1.0f / fmaxf(sqrtf(sq2[tid] + sq2[tid + 64] + sq2[tid + 128] + sq2[tid + 192]), 1e-12f);
    __syncthreads();

    unsigned char* dst = Wbf + ((size_t)k * NCB + cb) * 16384;
    #pragma unroll
    for (int i = 0; i < 4; i++) {
        int idx = i * 256 + tid;
        int ccol = ((idx >> 9) << 5) + (((idx >> 8) & 1) << 4) + (idx & 15);
        float wi = wis[ccol];
        uint4 u = wout[idx];
        uint4 r;
        r.x = scale2(u.x, wi);
        r.y = scale2(u.y, wi);
        r.z = scale2(u.z, wi);
        r.w = scale2(u.w, wi);
        *(uint4*)(dst + (size_t)idx * 16) = r;
    }
}

// ---------------------------------------------------------------------------
// Kernel B: r13 structure with 64x16 wave tiles (2 m-halves x 4 n-slots).
// Halves LDS B-reads: 4 ds_read_b128 per wave per k (was 8) — the r13 LDS
// pipe (25.3 us) was the largest consumer. af grows to 4x4 (64 VGPR).
__global__ __launch_bounds__(512, 2) void gemm_mx(
    const float* __restrict__ X, const unsigned char* __restrict__ Wbf,
    const int* __restrict__ label, const float* __restrict__ xinv,
    float2* __restrict__ partial, float* __restrict__ cosl) {

    __shared__ union {
        short xs[128 * LDX];   // 34816 B, X staging
        short bb[2][8192];     // 2 x 16 KB B buffers
    } u;

    const int tid  = threadIdx.x;
    const int lane = tid & 63;
    const int w    = tid >> 6;     // 0..7
    const int l15  = lane & 15;
    const int q    = lane >> 4;
    const int wm   = w & 1;        // 2 m-halves (64 rows each)
    const int wn4  = w >> 1;       // 4 n-slots (16 cols each)

    // XCD-aware decode: ids {group*64 + y*8 + xcd} -> cb = group*8 + xcd
    const int id    = blockIdx.x;
    const int group = id >> 6;
    const int sub   = id & 63;
    const int cb    = group * 8 + (sub & 7);
    const int y     = sub >> 3;            // 0..7
    if (cb >= NCB) return;
    const int r0 = y * 128;
    const int o0 = cb * 64;

    // ---- stage X tile (128 rows) as bf16 with xinv folded ----
    #pragma unroll
    for (int it = 0; it < 8; it++) {
        int idx = it * 512 + tid;      // float4 index 0..4095
        int row = idx >> 5;
        int c4  = idx & 31;
        const float4 v = *(const float4*)(X + (size_t)(r0 + row) * FIN + c4 * 4);
        float xi = xinv[r0 + row];
        uint2 p;
        p.x = packbf(v.x * xi, v.y * xi);
        p.y = packbf(v.z * xi, v.w * xi);
        *(uint2*)(u.xs + row * LDX + c4 * 4) = p;
    }
    __syncthreads();

    short8 af[4][4];
    #pragma unroll
    for (int mt = 0; mt < 4; mt++)
        #pragma unroll
        for (int kk = 0; kk < 4; kk++)
            af[mt][kk] = *(const short8*)(u.xs + (wm * 64 + mt * 16 + l15) * LDX + kk * 32 + q * 8);
    __syncthreads();   // X area now reusable as B buffers

    // per-step B staging: 16 KB; wave w loads 2 KB (2 async16 calls)
    auto issue = [&](int k) {
        const unsigned char* g = Wbf + ((size_t)k * NCB + cb) * 16384
                                 + (size_t)w * 2048 + (size_t)lane * 16;
        short* d = u.bb[k & 1] + w * 1024;
        async16(g, d);
        async16(g + 1024, d + 512);
    };

    issue(0);

    floatx4 maxv[4];
    #pragma unroll
    for (int mt = 0; mt < 4; mt++)
        #pragma unroll
        for (int r = 0; r < 4; r++)
            maxv[mt][r] = -INFINITY;

    for (int k = 0; k < NK; k++) {
        __syncthreads();   // loads(k) landed; prior buffer reads done
        if (k < NK - 1) issue(k + 1);
        const short* wt = u.bb[k & 1];

        floatx4 acc[4];
        #pragma unroll
        for (int mt = 0; mt < 4; mt++) acc[mt] = (floatx4){0.f, 0.f, 0.f, 0.f};
        #pragma unroll
        for (int kk = 0; kk < 4; kk++) {
            short8 bf = *(const short8*)(wt + wn4 * 1024 + kk * 256 + lane * 8);
            #pragma unroll
            for (int mt = 0; mt < 4; mt++)
                acc[mt] = __builtin_amdgcn_mfma_f32_16x16x32_bf16(af[mt][kk], bf, acc[mt], 0, 0, 0);
        }
        #pragma unroll
        for (int mt = 0; mt < 4; mt++)
            #pragma unroll
            for (int r = 0; r < 4; r++)
                maxv[mt][r] = fmaxf(maxv[mt][r], acc[mt][r]);
    }

    // ---- epilogue: fixed-reference partial softmax (label col excluded) ----
    const int o = o0 + wn4 * 16 + l15;   // this lane's column
    #pragma unroll
    for (int mt = 0; mt < 4; mt++) {
        #pragma unroll
        for (int rr = 0; rr < 4; rr++) {
            int row = r0 + wm * 64 + mt * 16 + q * 4 + rr;
            int lb = label[row];
            float m = -1e30f, sum = 0.f;
            if (o < NOUT) {
                float cc = maxv[mt][rr];
                if (o == lb) {
                    cosl[row] = cc;   // unique writer grid-wide
                } else {
                    float l = 64.0f * fminf(fmaxf(cc, -1.0f + 1e-6f), 1.0f - 1e-6f);
                    sum = __expf(l - 64.0f);
                    m = l;
                }
            }
            #pragma unroll
            for (int off = 1; off <= 8; off <<= 1) {
                sum += __shfl_xor(sum, off);
                m = fmaxf(m, __shfl_xor(m, off));
            }
            if (l15 == 0)
                partial[(size_t)row * NP_FX + cb * 4 + wn4] = make_float2(m, sum);
        }
    }
}

// ---------------------------------------------------------------------------
// Fallback GEMM (used when ws_size can't hold Wbf). Stride NP_FB partials.
__global__ __launch_bounds__(256, 2) void gemm_stats(
    const float* __restrict__ X, const float* __restrict__ W,
    const int* __restrict__ label, const float* __restrict__ xinv,
    float2* __restrict__ partial, float* __restrict__ cosl) {

    __shared__ short xs[128 * LDX];
    __shared__ short wt[128 * LDX];
    __shared__ float sqs[128][2];

    const int tid  = threadIdx.x;
    const int lane = tid & 63;
    const int w    = tid >> 6;
    const int l15  = lane & 15;
    const int q    = lane >> 4;
    const int wm   = w & 1;
    const int wn   = w >> 1;

    const int id    = blockIdx.x;
    const int group = id >> 6;
    const int sub   = id & 63;
    const int jb    = group * 8 + (sub & 7);
    const int y     = sub >> 3;
    if (jb >= NBLK) return;
    const int r0 = y * 128;
    const int o0 = jb * 128;

    #pragma unroll
    for (int it = 0; it < 16; it++) {
        int idx = it * 256 + tid;
        int row = idx >> 5;
        int c4  = idx & 31;
        const float4 v = *(const float4*)(X + (size_t)(r0 + row) * FIN + c4 * 4);
        uint2 p;
        p.x = packbf(v.x, v.y);
        p.y = packbf(v.z, v.w);
        *(uint2*)(xs + row * LDX + c4 * 4) = p;
    }

    const int st_o = (w & 1) * 64 + lane;
    const int st_f = (w >> 1) * 64;
    const int st_h = w >> 1;
    const int go   = o0 + st_o;
    const bool ov  = go < NOUT;

    float rw[64];
    {
        const float* Wp = W + (size_t)st_f * NOUT + go;
        #pragma unroll
        for (int g = 0; g < 16; g++)
            #pragma unroll
            for (int cc = 0; cc < 4; cc++)
                rw[g * 4 + cc] = ov ? Wp[(size_t)(g * 4 + cc) * NOUT] : 0.0f;
    }
    __syncthreads();

    short8 af[4][4];
    #pragma unroll
    for (int mt = 0; mt < 4; mt++)
        #pragma unroll
        for (int kk = 0; kk < 4; kk++)
            af[mt][kk] = *(const short8*)(xs + (wm * 64 + mt * 16 + l15) * LDX + kk * 32 + q * 8);

    floatx4 maxv[4][4];
    #pragma unroll
    for (int mt = 0; mt < 4; mt++)
        #pragma unroll
        for (int nt = 0; nt < 4; nt++)
            #pragma unroll
            for (int r = 0; r < 4; r++)
                maxv[mt][nt][r] = -INFINITY;

    for (int k = 0; k < NK; k++) {
        float sq = 0.0f;
        uint2 pk[16];
        #pragma unroll
        for (int g = 0; g < 16; g++) {
            float a0 = rw[g * 4 + 0], a1 = rw[g * 4 + 1];
            float a2 = rw[g * 4 + 2], a3 = rw[g * 4 + 3];
            sq = fmaf(a0, a0, sq); sq = fmaf(a1, a1, sq);
            sq = fmaf(a2, a2, sq); sq = fmaf(a3, a3, sq);
            pk[g].x = packbf(a0, a1);
            pk[g].y = packbf(a2, a3);
        }
        __syncthreads();
        #pragma unroll
        for (int g = 0; g < 16; g++)
            *(uint2*)(wt + st_o * LDX + st_f + g * 4) = pk[g];
        sqs[st_o][st_h] = sq;
        __syncthreads();

        if (k < NK - 1) {
            const float* Wn = W + ((size_t)(k + 1) * FIN + st_f) * NOUT + go;
            #pragma unroll
            for (int g = 0; g < 16; g++)
                #pragma unroll
                for (int cc = 0; cc < 4; cc++)
                    rw[g * 4 + cc] = ov ? Wn[(size_t)(g * 4 + cc) * NOUT] : 0.0f;
        }

        float wv[4];
        #pragma unroll
        for (int nt = 0; nt < 4; nt++) {
            int colx = wn * 64 + nt * 16 + l15;
            wv[nt] = 1.0f / fmaxf(sqrtf(sqs[colx][0] + sqs[colx][1]), 1e-12f);
        }

        #pragma unroll
        for (int h = 0; h < 2; h++) {
            floatx4 acc[4][2];
            #pragma unroll
            for (int mt = 0; mt < 4; mt++) {
                acc[mt][0] = (floatx4){0.f, 0.f, 0.f, 0.f};
                acc[mt][1] = (floatx4){0.f, 0.f, 0.f, 0.f};
            }
            #pragma unroll
            for (int kk = 0; kk < 4; kk++) {
                short8 bf0 = *(const short8*)(wt + (wn * 64 + (h * 2 + 0) * 16 + l15) * LDX + kk * 32 + q * 8);
                short8 bf1 = *(const short8*)(wt + (wn * 64 + (h * 2 + 1) * 16 + l15) * LDX + kk * 32 + q * 8);
                #pragma unroll
                for (int mt = 0; mt < 4; mt++) {
                    acc[mt][0] = __builtin_amdgcn_mfma_f32_16x16x32_bf16(af[mt][kk], bf0, acc[mt][0], 0, 0, 0);
                    acc[mt][1] = __builtin_amdgcn_mfma_f32_16x16x32_bf16(af[mt][kk], bf1, acc[mt][1], 0, 0, 0);
                }
            }
            #pragma unroll
            for (int mt = 0; mt < 4; mt++)
                #pragma unroll
                for (int n2 = 0; n2 < 2; n2++)
                    #pragma unroll
                    for (int r = 0; r < 4; r++)
                        maxv[mt][h * 2 + n2][r] =
                            fmaxf(maxv[mt][h * 2 + n2][r], acc[mt][n2][r] * wv[h * 2 + n2]);
        }
    }

    #pragma unroll
    for (int mt = 0; mt < 4; mt++) {
        #pragma unroll
        for (int rr = 0; rr < 4; rr++) {
            int row = r0 + wm * 64 + mt * 16 + q * 4 + rr;
            float xi = xinv[row];
            int lb = label[row];
            float m = -1e30f, sum = 0.f;
            #pragma unroll
            for (int nt = 0; nt < 4; nt++) {
                int o = o0 + wn * 64 + nt * 16 + l15;
                if (o < NOUT) {
                    float cc = maxv[mt][nt][rr] * xi;
                    if (o == lb) {
                        cosl[row] = cc;
                    } else {
                        float l = 64.0f * fminf(fmaxf(cc, -1.0f + 1e-6f), 1.0f - 1e-6f);
                        sum += __expf(l - 64.0f);
                        m = fmaxf(m, l);
                    }
                }
            }
            #pragma unroll
            for (int off = 1; off <= 8; off <<= 1) {
                sum += __shfl_xor(sum, off);
                m = fmaxf(m, __shfl_xor(m, off));
            }
            if (l15 == 0) {
                partial[(size_t)row * NP_FB + jb * 4 + wn * 2 + 0] = make_float2(m, sum);
                partial[(size_t)row * NP_FB + jb * 4 + wn * 2 + 1] = make_float2(-1e30f, 0.f);
            }
        }
    }
}

// ---------------------------------------------------------------------------
// Kernel C1: per-row combine (fixed-ref: plain sum+max) + margin. np = stride.
__global__ void finalize_rows(const float2* __restrict__ partial, const float* __restrict__ cosl,
                              const float* __restrict__ fa, const float* __restrict__ thr,
                              float2* __restrict__ rowres, int np) {
    int w = threadIdx.x >> 6;
    int lane = threadIdx.x & 63;
    int b = blockIdx.x * 4 + w;
    float m = -1e30f, s = 0.0f;
    for (int j = lane; j < np; j += 64) {
        float2 p = partial[(size_t)b * np + j];
        s += p.y;
        m = fmaxf(m, p.x);
    }
    #pragma unroll
    for (int off = 1; off < 64; off <<= 1) {
        s += __shfl_xor(s, off);
        m = fmaxf(m, __shfl_xor(m, off));
    }
    if (lane == 0) {
        float c = fminf(fmaxf(cosl[b], -1.0f + 1e-6f), 1.0f - 1e-6f);
        float theta = acosf(c);
        float ll = (theta > thr[b]) ? 64.0f * c : 64.0f * cosf(theta + fa[b]);
        float S = s + __expf(ll - 64.0f);
        float loss = 64.0f + logf(S) - ll;
        rowres[b] = make_float2(loss, (ll > m) ? 100.0f : 0.0f);
    }
}

// Kernel C2: deterministic tree reduce of 1024 rows -> 2 scalars.
__global__ void finalize_sum(const float2* __restrict__ rowres, float* __restrict__ out) {
    __shared__ float sl[1024];
    __shared__ float sc[1024];
    int b = threadIdx.x;
    float2 v = rowres[b];
    sl[b] = v.x;
    sc[b] = v.y;
    __syncthreads();
    for (int st = 512; st > 0; st >>= 1) {
        if (b < st) { sl[b] += sl[b + st]; sc[b] += sc[b + st]; }
        __syncthreads();
    }
    if (b == 0) {
        out[0] = sl[0] * (1.0f / 1024.0f);
        out[1] = sc[0] * (1.0f / 1024.0f);
    }
}

// ---------------------------------------------------------------------------
extern "C" void kernel_launch(void* const* d_in, const int* in_sizes, int n_in,
                              void* d_out, int out_size, void* d_ws, size_t ws_size,
                              hipStream_t stream) {
    const float* X      = (const float*)d_in[0];
    const float* factor = (const float*)d_in[1];
    const int*   label  = (const int*)d_in[2];
    const float* W      = (const float*)d_in[3];
    float* out = (float*)d_out;
    float* ws  = (float*)d_ws;

    float*  xinv = ws;                        // 1024
    float*  fa   = ws + 1024;                 // 1024
    float*  thr  = ws + 2048;                 // 1024
    float*  cosl = ws + 3072;                 // 1024
    float2* rowres = (float2*)(ws + 4096);    // 1024 float2
    float2* partial = (float2*)(ws + 6144);   // 1024 x 632 float2 (~5.2 MB)
    unsigned char* Wbf = (unsigned char*)d_ws + 6 * 1024 * 1024;  // 41.4 MB

    const size_t wbf_bytes = (size_t)NK * NCB * 16384;
    const size_t need = 6ull * 1024 * 1024 + wbf_bytes;

    if (ws_size >= need) {
        wconv<<<NK * NCB + 16, 256, 0, stream>>>(W, Wbf, X, factor, xinv, fa, thr);
        gemm_mx<<<1280, 512, 0, stream>>>(X, Wbf, label, xinv, partial, cosl);
        finalize_rows<<<BB / 4, 256, 0, stream>>>(partial, cosl, fa, thr, rowres, NP_FX);
    } else {
        rowprep<<<BB, 64, 0, stream>>>(X, factor, xinv, fa, thr);
        gemm_stats<<<640, 256, 0, stream>>>(X, W, label, xinv, partial, cosl);
        finalize_rows<<<BB / 4, 256, 0, stream>>>(partial, cosl, fa, thr, rowres, NP_FB);
    }
    finalize_sum<<<1, BB, 0, stream>>>(rowres, out);
}